// Round 9
// baseline (119.616 us; speedup 1.0000x reference)
//
#include <hip/hip_runtime.h>

// ForwardDistance: out[b,n,m] = sum_a agg[a] * tanh(datalin[b,n,a] + critlin[b,m,a])
// tanh(x+y) = 1 - 2/(1 + e^{2x} e^{2y})
// R9: E planes stored fp32 (staging = pure float4 copy, no bf16 unpack VALU) and
//   tanh staging register-prefetches the next a-chunk during compute (1 block/CU
//   has nothing else to hide global latency). proj main loop / transpose_w are
//   R8's proven code; proj epilogue now does two 16B fp32 stores.

#define A_DIM 256
#define K_DIM 512
#define NROWS 2048   // rows per source (B*N == B*M)

typedef unsigned short ushort;
typedef __attribute__((ext_vector_type(4))) unsigned short us4;
typedef __attribute__((ext_vector_type(8))) unsigned short us8;
typedef __attribute__((ext_vector_type(8))) short short8;   // bf16x8 MFMA frag
typedef __attribute__((ext_vector_type(4))) float f32x4;    // MFMA acc

__device__ inline ushort f2bf(float x) {    // round-to-nearest-even bf16
    union { float f; unsigned u; } v; v.f = x;
    unsigned r = v.u + 0x7FFFu + ((v.u >> 16) & 1u);
    return (ushort)(r >> 16);
}
__device__ inline unsigned pack2bf(float lo, float hi) {
    return (unsigned)f2bf(lo) | ((unsigned)f2bf(hi) << 16);
}

// ---- W[k][a] fp32 -> Wt[a][k] bf16, once ----
__global__ __launch_bounds__(256) void transpose_w_kernel(
    const float* __restrict__ Wl, const float* __restrict__ Wr,
    ushort* __restrict__ wt)
{
    __shared__ float tile[64][68];
    const int t   = threadIdx.x;
    const int bid = blockIdx.x;
    const int at  = bid & 3;          // a tile
    const int kt  = (bid >> 2) & 7;   // k tile
    const int src = bid >> 5;
    const int a0 = at * 64, k0 = kt * 64;
    const float* W = src ? Wr : Wl;
    ushort* out = wt + (size_t)src * (A_DIM * K_DIM);

    const int c4 = (t & 15) * 4;
    const int kr = t >> 4;
#pragma unroll
    for (int r = 0; r < 4; r++) {
        const int k = kr + r * 16;
        *(float4*)&tile[k][c4] = *(const float4*)(W + (size_t)(k0 + k) * A_DIM + a0 + c4);
    }
    __syncthreads();
    const int aL  = t & 63;           // lane -> consecutive dwords: conflict-free
    const int ks0 = (t >> 6) * 16;
#pragma unroll
    for (int g = 0; g < 4; g++) {
        us4 o;
#pragma unroll
        for (int i = 0; i < 4; i++) o[i] = f2bf(tile[ks0 + g * 4 + i][aL]);
        *(us4*)(out + (size_t)(a0 + aL) * K_DIM + k0 + ks0 + g * 4) = o;
    }
}

// ---- bf16 MFMA GEMM + exp2 epilogue -> Ed/Ec fp32 planes [a][row] ----
__global__ __launch_bounds__(256) void proj_mfma_kernel(
    const float* __restrict__ data, const float* __restrict__ crit,
    const float* __restrict__ bl, const float* __restrict__ br,
    const ushort* __restrict__ wt, float* __restrict__ eplanes)
{
    __shared__ ushort Ws[64][264];   // [a][k-chunk 256], pad 264

    const int t   = threadIdx.x;
    const int bid = blockIdx.x;
    const int ct  = bid & 3;         // a-col tile (64)
    const int rt  = bid >> 2;        // 0..127 row tile (32 rows)
    const int src = rt >> 6;
    const int lr0 = (rt & 63) * 32;
    const int c0  = ct * 64;

    const float* X    = src ? crit : data;
    const float* bias = src ? br : bl;
    const ushort* Wt  = wt + (size_t)src * (A_DIM * K_DIM);
    float* E = eplanes + (size_t)src * ((size_t)A_DIM * NROWS);

    const int lane = t & 63;
    const int wid  = t >> 6;             // 4 waves: 2 (rows) x 2 (cols)
    const int wm   = wid >> 1, wn = wid & 1;
    const int quad = lane >> 4, l16 = lane & 15;

    const float* xrow = X + (size_t)(lr0 + wm * 16 + l16) * K_DIM + quad * 8;
    const int aloc0 = wn * 32 + l16;

    f32x4 acc0 = {0.f, 0.f, 0.f, 0.f}, acc1 = {0.f, 0.f, 0.f, 0.f};

    float4 pa = *(const float4*)(xrow);
    float4 pb = *(const float4*)(xrow + 4);

    for (int kc = 0; kc < 2; kc++) {     // two 256-k LDS chunks of W
        __syncthreads();
        {   // stage Ws[a][0..255] from Wt[c0+a][kc*256 ..]
            const int a  = t & 63;
            const int ks = (t >> 6) * 64;
            const ushort* s = Wt + (size_t)(c0 + a) * K_DIM + kc * 256 + ks;
#pragma unroll
            for (int i = 0; i < 8; i++)
                *(us8*)&Ws[a][ks + i * 8] = *(const us8*)(s + i * 8);
        }
        __syncthreads();

#pragma unroll
        for (int ls = 0; ls < 8; ls++) {
            const int s = kc * 8 + ls;
            float4 ca = pa, cb = pb;
            if (s < 15) {                // rolling A prefetch
                pa = *(const float4*)(xrow + (s + 1) * 32);
                pb = *(const float4*)(xrow + (s + 1) * 32 + 4);
            }
            union { short8 s8; unsigned u[4]; } af;
            af.u[0] = pack2bf(ca.x, ca.y);
            af.u[1] = pack2bf(ca.z, ca.w);
            af.u[2] = pack2bf(cb.x, cb.y);
            af.u[3] = pack2bf(cb.z, cb.w);
            short8 b0 = *(const short8*)&Ws[aloc0     ][ls * 32 + quad * 8];
            short8 b1 = *(const short8*)&Ws[aloc0 + 16][ls * 32 + quad * 8];
            acc0 = __builtin_amdgcn_mfma_f32_16x16x32_bf16(af.s8, b0, acc0, 0, 0, 0);
            acc1 = __builtin_amdgcn_mfma_f32_16x16x32_bf16(af.s8, b1, acc1, 0, 0, 0);
        }
    }

    // epilogue: C/D layout col=lane&15 (a), row=quad*4+reg. fp32 E stores.
    const float c2 = 2.8853900817779268f;    // 2*log2(e)
    const int a_col0 = c0 + wn * 32 + l16;
    const int a_col1 = a_col0 + 16;
    const int row0   = lr0 + wm * 16 + quad * 4;
    const float bv0 = bias[a_col0], bv1 = bias[a_col1];
    f32x4 e0, e1;
#pragma unroll
    for (int i = 0; i < 4; i++) {
        float v0 = (acc0[i] + bv0) * c2;
        float v1 = (acc1[i] + bv1) * c2;
        v0 = fminf(fmaxf(v0, -15.f), 15.f);   // bounds q<=1+2^30 for rcp path
        v1 = fminf(fmaxf(v1, -15.f), 15.f);
        e0[i] = __builtin_amdgcn_exp2f(v0);
        e1[i] = __builtin_amdgcn_exp2f(v1);
    }
    *(f32x4*)(E + (size_t)a_col0 * NROWS + row0) = e0;
    *(f32x4*)(E + (size_t)a_col1 * NROWS + row0) = e1;
}

// ---- tanh-reduce: 512 thr, 64x64 tile, a-halves across wave-halves,
//      register-prefetched staging ----
__global__ __launch_bounds__(512) void tanh_reduce_kernel(
    const float* __restrict__ eplanes, const float* __restrict__ agg,
    float* __restrict__ out)
{
    __shared__ __align__(16) float et [2][64][68];   // [half][a][n]
    __shared__ __align__(16) float ect[2][64][68];   // [half][a][m]
    __shared__ float aggs[256];

    const int t  = threadIdx.x;
    const int h  = t >> 8;               // a-half (0: a<128, 1: a>=128)
    const int u  = t & 255;              // thread id within half
    const int m0 = blockIdx.x * 64;
    const int n0 = blockIdx.y * 64;
    const int b  = blockIdx.z;

    const size_t PLANE = (size_t)A_DIM * NROWS;
    const float* Ed = eplanes;
    const float* Ec = eplanes + PLANE;
    const int row_n = b * 512 + n0;
    const int row_m = b * 512 + m0;

    const int tx = u & 15;               // m group (4 m's)
    const int ty = u >> 4;               // n group (4 n's)

    if (t < 256) aggs[t] = 2.0f * agg[t];

    float acc[4][4];
#pragma unroll
    for (int i = 0; i < 4; i++)
#pragma unroll
        for (int j = 0; j < 4; j++) acc[i][j] = 0.f;
    float sagg = 0.f;

    const int aL = u >> 2;               // staging row 0..63
    const int qd = u & 3;                // staging quarter

    float (*eth)[68]  = et[h];
    float (*ecth)[68] = ect[h];

    // prefetch regs: 8 float4 (one full chunk's staging share)
    float4 pn[4], pm[4];
#pragma unroll
    for (int r = 0; r < 4; r++) {
        const size_t base = (size_t)(h * 128 + aL) * NROWS;
        pn[r] = *(const float4*)(Ed + base + row_n + qd * 16 + r * 4);
        pm[r] = *(const float4*)(Ec + base + row_m + qd * 16 + r * 4);
    }

    for (int ch = 0; ch < 2; ch++) {
        __syncthreads();                 // prev chunk's LDS reads done (+aggs on ch0)
#pragma unroll
        for (int r = 0; r < 4; r++) {
            *(float4*)&eth [aL][qd * 16 + r * 4] = pn[r];
            *(float4*)&ecth[aL][qd * 16 + r * 4] = pm[r];
        }
        __syncthreads();
        if (ch == 0) {                   // prefetch next chunk during compute
            const size_t base = (size_t)(h * 128 + 64 + aL) * NROWS;
#pragma unroll
            for (int r = 0; r < 4; r++) {
                pn[r] = *(const float4*)(Ed + base + row_n + qd * 16 + r * 4);
                pm[r] = *(const float4*)(Ec + base + row_m + qd * 16 + r * 4);
            }
        }

        for (int p = 0; p < 32; p++) {   // pair-grouped: one rcp per 2 a-terms
            const float2 ag = *(const float2*)&aggs[h * 128 + ch * 64 + p * 2];
            sagg += ag.x + ag.y;
            float4 e0 = *(const float4*)&eth [p * 2 + 0][ty * 4];
            float4 e1 = *(const float4*)&eth [p * 2 + 1][ty * 4];
            float4 f0 = *(const float4*)&ecth[p * 2 + 0][tx * 4];
            float4 f1 = *(const float4*)&ecth[p * 2 + 1][tx * 4];
            const float ea0[4] = {e0.x, e0.y, e0.z, e0.w};
            const float ea1[4] = {e1.x, e1.y, e1.z, e1.w};
            const float fa0[4] = {f0.x, f0.y, f0.z, f0.w};
            const float fa1[4] = {f1.x, f1.y, f1.z, f1.w};
#pragma unroll
            for (int i = 0; i < 4; i++)
#pragma unroll
                for (int j = 0; j < 4; j++) {
                    float q0 = fmaf(ea0[i], fa0[j], 1.f);
                    float q1 = fmaf(ea1[i], fa1[j], 1.f);
                    acc[i][j] = fmaf(fmaf(ag.x, q1, ag.y * q0),
                                     __builtin_amdgcn_rcpf(q0 * q1), acc[i][j]);
                }
        }
    }

    // partial_h = 0.5*sagg - acc ; merge halves via LDS (stride 17: conflict-free)
    const float base = 0.5f * sagg;
    float* xb = (float*)ect;             // reuse
    __syncthreads();                     // all LDS reads of et/ect complete
    if (h == 1) {
#pragma unroll
        for (int i = 0; i < 4; i++)
#pragma unroll
            for (int j = 0; j < 4; j++)
                xb[u * 17 + i * 4 + j] = base - acc[i][j];
    }
    __syncthreads();
    if (h == 0) {
#pragma unroll
        for (int i = 0; i < 4; i++) {
            float4 v;
            v.x = (base - acc[i][0]) + xb[u * 17 + i * 4 + 0];
            v.y = (base - acc[i][1]) + xb[u * 17 + i * 4 + 1];
            v.z = (base - acc[i][2]) + xb[u * 17 + i * 4 + 2];
            v.w = (base - acc[i][3]) + xb[u * 17 + i * 4 + 3];
            *(float4*)(out + ((size_t)(b * 512 + n0 + ty * 4 + i) * 512) + m0 + tx * 4) = v;
        }
    }
}

extern "C" void kernel_launch(void* const* d_in, const int* in_sizes, int n_in,
                              void* d_out, int out_size, void* d_ws, size_t ws_size,
                              hipStream_t stream) {
    const float* data = (const float*)d_in[0];
    const float* crit = (const float*)d_in[1];
    const float* Wl   = (const float*)d_in[2];
    const float* bl   = (const float*)d_in[3];
    const float* Wr   = (const float*)d_in[4];
    const float* br   = (const float*)d_in[5];
    const float* agg  = (const float*)d_in[6];
    float* out = (float*)d_out;

    // ws layout: Ed fp32 [256][2048] (2 MB) | Ec (2 MB) | Wt bf16 2x[256][512] (1 MB)
    float*  eplanes = (float*)d_ws;
    ushort* wt      = (ushort*)((char*)d_ws + 8u * 1024u * 1024u);

    // W transpose+cast: 8 k-tiles x 4 a-tiles x 2 src = 64 blocks
    transpose_w_kernel<<<dim3(64), 256, 0, stream>>>(Wl, Wr, wt);

    // proj: 128 row-tiles(32) x 4 col-tiles(64) = 512 blocks
    proj_mfma_kernel<<<dim3(512), 256, 0, stream>>>(data, crit, bl, br, wt, eplanes);

    // tanh: (8 m x 8 n) x 4 b = 256 blocks x 512 threads; writes out directly
    tanh_reduce_kernel<<<dim3(8, 8, 4), 512, 0, stream>>>(eplanes, agg, out);
}

// Round 11
// 107.790 us; speedup vs baseline: 1.1097x; 1.1097x over previous
//
#include <hip/hip_runtime.h>

// ForwardDistance: out[b,n,m] = sum_a agg[a] * tanh(datalin[b,n,a] + critlin[b,m,a])
// tanh(x+y) = 1 - 2/(1 + e^{2x} e^{2y})
// R11 == R10 with the compile fix: NT store of `out` goes through ext_vector f32x4
//   (clang's __builtin_nontemporal_store rejects HIP_vector_type float4).
// R10 theory: (a) bf16 E planes + NON-TEMPORAL stores for ws producer->consumer
//   traffic (R9: proj's dirty L2 lines forced cross-XCD coherence writebacks,
//   WRITE_SIZE 34 MB @ 1.2 TB/s). (b) tanh inner loop quad-grouped (1 rcp / 4
//   a-terms) with f32x2 packed math (v_pk_fma_f32): VALU floor 17 -> 9.4 us.
//   q <= 1+2^30 each, D = q0q1q2q3 <= 2^121 < FLT_MAX.

#define A_DIM 256
#define K_DIM 512
#define NROWS 2048   // rows per source (B*N == B*M)

typedef unsigned short ushort;
typedef __attribute__((ext_vector_type(4))) unsigned short us4;
typedef __attribute__((ext_vector_type(8))) unsigned short us8;
typedef __attribute__((ext_vector_type(8))) short short8;   // bf16x8 MFMA frag
typedef __attribute__((ext_vector_type(4))) float f32x4;    // MFMA acc / NT stores
typedef __attribute__((ext_vector_type(2))) float f32x2;    // packed fp32

__device__ inline ushort f2bf(float x) {    // round-to-nearest-even bf16
    union { float f; unsigned u; } v; v.f = x;
    unsigned r = v.u + 0x7FFFu + ((v.u >> 16) & 1u);
    return (ushort)(r >> 16);
}
__device__ inline float bf2f(ushort h) {
    union { unsigned u; float f; } v; v.u = ((unsigned)h) << 16; return v.f;
}
__device__ inline unsigned pack2bf(float lo, float hi) {
    return (unsigned)f2bf(lo) | ((unsigned)f2bf(hi) << 16);
}
__device__ inline f32x2 fma2(f32x2 a, f32x2 b, f32x2 c) {
    return __builtin_elementwise_fma(a, b, c);
}

// ---- W[k][a] fp32 -> Wt[a][k] bf16, once ----
__global__ __launch_bounds__(256) void transpose_w_kernel(
    const float* __restrict__ Wl, const float* __restrict__ Wr,
    ushort* __restrict__ wt)
{
    __shared__ float tile[64][68];
    const int t   = threadIdx.x;
    const int bid = blockIdx.x;
    const int at  = bid & 3;          // a tile
    const int kt  = (bid >> 2) & 7;   // k tile
    const int src = bid >> 5;
    const int a0 = at * 64, k0 = kt * 64;
    const float* W = src ? Wr : Wl;
    ushort* out = wt + (size_t)src * (A_DIM * K_DIM);

    const int c4 = (t & 15) * 4;
    const int kr = t >> 4;
#pragma unroll
    for (int r = 0; r < 4; r++) {
        const int k = kr + r * 16;
        *(float4*)&tile[k][c4] = *(const float4*)(W + (size_t)(k0 + k) * A_DIM + a0 + c4);
    }
    __syncthreads();
    const int aL  = t & 63;
    const int ks0 = (t >> 6) * 16;
#pragma unroll
    for (int g = 0; g < 4; g++) {
        us4 o;
#pragma unroll
        for (int i = 0; i < 4; i++) o[i] = f2bf(tile[ks0 + g * 4 + i][aL]);
        __builtin_nontemporal_store(o, (us4*)(out + (size_t)(a0 + aL) * K_DIM + k0 + ks0 + g * 4));
    }
}

// ---- bf16 MFMA GEMM + exp2 epilogue -> Ed/Ec bf16 planes [a][row] ----
__global__ __launch_bounds__(256) void proj_mfma_kernel(
    const float* __restrict__ data, const float* __restrict__ crit,
    const float* __restrict__ bl, const float* __restrict__ br,
    const ushort* __restrict__ wt, ushort* __restrict__ eplanes)
{
    __shared__ ushort Ws[64][264];   // [a][k-chunk 256], pad 264

    const int t   = threadIdx.x;
    const int bid = blockIdx.x;
    const int ct  = bid & 3;         // a-col tile (64)
    const int rt  = bid >> 2;        // 0..127 row tile (32 rows)
    const int src = rt >> 6;
    const int lr0 = (rt & 63) * 32;
    const int c0  = ct * 64;

    const float* X    = src ? crit : data;
    const float* bias = src ? br : bl;
    const ushort* Wt  = wt + (size_t)src * (A_DIM * K_DIM);
    ushort* E = eplanes + (size_t)src * ((size_t)A_DIM * NROWS);

    const int lane = t & 63;
    const int wid  = t >> 6;             // 4 waves: 2 (rows) x 2 (cols)
    const int wm   = wid >> 1, wn = wid & 1;
    const int quad = lane >> 4, l16 = lane & 15;

    const float* xrow = X + (size_t)(lr0 + wm * 16 + l16) * K_DIM + quad * 8;
    const int aloc0 = wn * 32 + l16;

    f32x4 acc0 = {0.f, 0.f, 0.f, 0.f}, acc1 = {0.f, 0.f, 0.f, 0.f};

    float4 pa = *(const float4*)(xrow);
    float4 pb = *(const float4*)(xrow + 4);

    for (int kc = 0; kc < 2; kc++) {     // two 256-k LDS chunks of W
        __syncthreads();
        {   // stage Ws[a][0..255] from Wt[c0+a][kc*256 ..]
            const int a  = t & 63;
            const int ks = (t >> 6) * 64;
            const ushort* s = Wt + (size_t)(c0 + a) * K_DIM + kc * 256 + ks;
#pragma unroll
            for (int i = 0; i < 8; i++)
                *(us8*)&Ws[a][ks + i * 8] = *(const us8*)(s + i * 8);
        }
        __syncthreads();

#pragma unroll
        for (int ls = 0; ls < 8; ls++) {
            const int s = kc * 8 + ls;
            float4 ca = pa, cb = pb;
            if (s < 15) {                // rolling A prefetch
                pa = *(const float4*)(xrow + (s + 1) * 32);
                pb = *(const float4*)(xrow + (s + 1) * 32 + 4);
            }
            union { short8 s8; unsigned u[4]; } af;
            af.u[0] = pack2bf(ca.x, ca.y);
            af.u[1] = pack2bf(ca.z, ca.w);
            af.u[2] = pack2bf(cb.x, cb.y);
            af.u[3] = pack2bf(cb.z, cb.w);
            short8 b0 = *(const short8*)&Ws[aloc0     ][ls * 32 + quad * 8];
            short8 b1 = *(const short8*)&Ws[aloc0 + 16][ls * 32 + quad * 8];
            acc0 = __builtin_amdgcn_mfma_f32_16x16x32_bf16(af.s8, b0, acc0, 0, 0, 0);
            acc1 = __builtin_amdgcn_mfma_f32_16x16x32_bf16(af.s8, b1, acc1, 0, 0, 0);
        }
    }

    // epilogue: C/D layout col=lane&15 (a), row=quad*4+reg. NT bf16 stores.
    const float c2 = 2.8853900817779268f;    // 2*log2(e)
    const int a_col0 = c0 + wn * 32 + l16;
    const int a_col1 = a_col0 + 16;
    const int row0   = lr0 + wm * 16 + quad * 4;
    const float bv0 = bias[a_col0], bv1 = bias[a_col1];
    us4 e0, e1;
#pragma unroll
    for (int i = 0; i < 4; i++) {
        float v0 = (acc0[i] + bv0) * c2;
        float v1 = (acc1[i] + bv1) * c2;
        v0 = fminf(fmaxf(v0, -15.f), 15.f);   // bounds q<=1+2^30 for rcp path
        v1 = fminf(fmaxf(v1, -15.f), 15.f);
        e0[i] = f2bf(__builtin_amdgcn_exp2f(v0));
        e1[i] = f2bf(__builtin_amdgcn_exp2f(v1));
    }
    __builtin_nontemporal_store(e0, (us4*)(E + (size_t)a_col0 * NROWS + row0));
    __builtin_nontemporal_store(e1, (us4*)(E + (size_t)a_col1 * NROWS + row0));
}

// ---- tanh-reduce: 512 thr, 64x64 tile, a-halves across wave-halves,
//      quad-grouped rcp + f32x2 packed math ----
__global__ __launch_bounds__(512) void tanh_reduce_kernel(
    const ushort* __restrict__ eplanes, const float* __restrict__ agg,
    float* __restrict__ out)
{
    __shared__ __align__(16) float et [2][64][68];   // [half][a][n]
    __shared__ __align__(16) float ect[2][64][68];   // [half][a][m]
    __shared__ __align__(16) float aggs[256];

    const int t  = threadIdx.x;
    const int h  = t >> 8;               // a-half (0: a<128, 1: a>=128)
    const int u  = t & 255;              // thread id within half
    const int m0 = blockIdx.x * 64;
    const int n0 = blockIdx.y * 64;
    const int b  = blockIdx.z;

    const size_t PLANE = (size_t)A_DIM * NROWS;
    const ushort* Ed = eplanes;
    const ushort* Ec = eplanes + PLANE;
    const int row_n = b * 512 + n0;
    const int row_m = b * 512 + m0;

    const int tx = u & 15;               // m group (4 m's)
    const int ty = u >> 4;               // n group (4 n's)

    if (t < 256) aggs[t] = 2.0f * agg[t];

    f32x2 acc2[4][2];                    // [n i][m j-pair]
#pragma unroll
    for (int i = 0; i < 4; i++) { acc2[i][0] = (f32x2)0.f; acc2[i][1] = (f32x2)0.f; }
    float sagg = 0.f;

    const int aL = u >> 2;               // staging row 0..63
    const int qd = u & 3;                // staging quarter

    float (*eth)[68]  = et[h];
    float (*ecth)[68] = ect[h];

    // register prefetch of one chunk's staging share (bf16: 8 B loads)
    us4 pn[4], pm[4];
#pragma unroll
    for (int r = 0; r < 4; r++) {
        const size_t base = (size_t)(h * 128 + aL) * NROWS;
        pn[r] = *(const us4*)(Ed + base + row_n + qd * 16 + r * 4);
        pm[r] = *(const us4*)(Ec + base + row_m + qd * 16 + r * 4);
    }

    for (int ch = 0; ch < 2; ch++) {
        __syncthreads();                 // prev chunk's LDS reads done (+aggs on ch0)
#pragma unroll
        for (int r = 0; r < 4; r++) {
            float4 ev, cv;
            ev.x = bf2f(pn[r][0]); ev.y = bf2f(pn[r][1]);
            ev.z = bf2f(pn[r][2]); ev.w = bf2f(pn[r][3]);
            cv.x = bf2f(pm[r][0]); cv.y = bf2f(pm[r][1]);
            cv.z = bf2f(pm[r][2]); cv.w = bf2f(pm[r][3]);
            *(float4*)&eth [aL][qd * 16 + r * 4] = ev;
            *(float4*)&ecth[aL][qd * 16 + r * 4] = cv;
        }
        __syncthreads();
        if (ch == 0) {                   // prefetch next chunk during compute
            const size_t base = (size_t)(h * 128 + 64 + aL) * NROWS;
#pragma unroll
            for (int r = 0; r < 4; r++) {
                pn[r] = *(const us4*)(Ed + base + row_n + qd * 16 + r * 4);
                pm[r] = *(const us4*)(Ec + base + row_m + qd * 16 + r * 4);
            }
        }

        for (int qg = 0; qg < 16; qg++) {    // a-quads: one rcp per 4 a-terms
            const float4 ag = *(const float4*)&aggs[h * 128 + ch * 64 + qg * 4];
            sagg += (ag.x + ag.y) + (ag.z + ag.w);
            float  en[4][4];                 // [a u][n i]
            f32x2  fm[4][2];                 // [a u][m j-pair]
#pragma unroll
            for (int v = 0; v < 4; v++) {
                float4 e4 = *(const float4*)&eth [qg * 4 + v][ty * 4];
                float4 f4 = *(const float4*)&ecth[qg * 4 + v][tx * 4];
                en[v][0] = e4.x; en[v][1] = e4.y; en[v][2] = e4.z; en[v][3] = e4.w;
                fm[v][0] = f32x2{f4.x, f4.y};
                fm[v][1] = f32x2{f4.z, f4.w};
            }
#pragma unroll
            for (int i = 0; i < 4; i++)
#pragma unroll
                for (int jp = 0; jp < 2; jp++) {
                    const f32x2 one = (f32x2)1.f;
                    f32x2 q0 = fma2((f32x2)en[0][i], fm[0][jp], one);
                    f32x2 q1 = fma2((f32x2)en[1][i], fm[1][jp], one);
                    f32x2 q2 = fma2((f32x2)en[2][i], fm[2][jp], one);
                    f32x2 q3 = fma2((f32x2)en[3][i], fm[3][jp], one);
                    f32x2 q01 = q0 * q1, q23 = q2 * q3;
                    f32x2 n01 = fma2((f32x2)ag.x, q1, (f32x2)ag.y * q0);
                    f32x2 n23 = fma2((f32x2)ag.z, q3, (f32x2)ag.w * q2);
                    f32x2 N   = fma2(n01, q23, n23 * q01);
                    f32x2 D   = q01 * q23;              // <= 2^121, no overflow
                    f32x2 r;
                    r.x = __builtin_amdgcn_rcpf(D.x);
                    r.y = __builtin_amdgcn_rcpf(D.y);
                    acc2[i][jp] = fma2(N, r, acc2[i][jp]);
                }
        }
    }

    // partial_h = 0.5*sagg - acc ; merge halves via LDS (stride 17: conflict-free)
    const float base = 0.5f * sagg;
    float* xb = (float*)ect;             // reuse
    __syncthreads();                     // all LDS reads of et/ect complete
    if (h == 1) {
#pragma unroll
        for (int i = 0; i < 4; i++)
#pragma unroll
            for (int jp = 0; jp < 2; jp++) {
                xb[u * 17 + i * 4 + jp * 2 + 0] = base - acc2[i][jp].x;
                xb[u * 17 + i * 4 + jp * 2 + 1] = base - acc2[i][jp].y;
            }
    }
    __syncthreads();
    if (h == 0) {
#pragma unroll
        for (int i = 0; i < 4; i++) {
            f32x4 v;
            v.x = (base - acc2[i][0].x) + xb[u * 17 + i * 4 + 0];
            v.y = (base - acc2[i][0].y) + xb[u * 17 + i * 4 + 1];
            v.z = (base - acc2[i][1].x) + xb[u * 17 + i * 4 + 2];
            v.w = (base - acc2[i][1].y) + xb[u * 17 + i * 4 + 3];
            __builtin_nontemporal_store(v,
                (f32x4*)(out + ((size_t)(b * 512 + n0 + ty * 4 + i) * 512) + m0 + tx * 4));
        }
    }
}

extern "C" void kernel_launch(void* const* d_in, const int* in_sizes, int n_in,
                              void* d_out, int out_size, void* d_ws, size_t ws_size,
                              hipStream_t stream) {
    const float* data = (const float*)d_in[0];
    const float* crit = (const float*)d_in[1];
    const float* Wl   = (const float*)d_in[2];
    const float* bl   = (const float*)d_in[3];
    const float* Wr   = (const float*)d_in[4];
    const float* br   = (const float*)d_in[5];
    const float* agg  = (const float*)d_in[6];
    float* out = (float*)d_out;

    // ws layout: Ed bf16 [256][2048] (1 MB) | Ec (1 MB) | Wt bf16 2x[256][512] (1 MB)
    ushort* eplanes = (ushort*)d_ws;
    ushort* wt      = eplanes + 2 * (size_t)A_DIM * NROWS;

    // W transpose+cast: 8 k-tiles x 4 a-tiles x 2 src = 64 blocks
    transpose_w_kernel<<<dim3(64), 256, 0, stream>>>(Wl, Wr, wt);

    // proj: 128 row-tiles(32) x 4 col-tiles(64) = 512 blocks
    proj_mfma_kernel<<<dim3(512), 256, 0, stream>>>(data, crit, bl, br, wt, eplanes);

    // tanh: (8 m x 8 n) x 4 b = 256 blocks x 512 threads; writes out directly
    tanh_reduce_kernel<<<dim3(8, 8, 4), 512, 0, stream>>>(eplanes, agg, out);
}